// Round 5
// baseline (385.649 us; speedup 1.0000x reference)
//
#include <hip/hip_runtime.h>

#define NEG 0.2f

using bf16x8 = __attribute__((ext_vector_type(8))) short;
using f32x4  = __attribute__((ext_vector_type(4))) float;

__device__ __forceinline__ short f2bf(float f) {   // RNE round to bf16 bits
    union { float f; unsigned u; } v; v.f = f;
    unsigned r = v.u + 0x7FFFu + ((v.u >> 16) & 1u);
    return (short)(r >> 16);
}
__device__ __forceinline__ float bflo(unsigned v) {
    union { unsigned u; float f; } x; x.u = v << 16; return x.f;
}
__device__ __forceinline__ float bfhi(unsigned v) {
    union { unsigned u; float f; } x; x.u = v & 0xffff0000u; return x.f;
}

// ---------------------------------------------------------------------------
// k_prep: Wbf[c*128+k] = bf16(W[k*128+c])  (one-time 64 KB -> 32 KB transpose)
// ---------------------------------------------------------------------------
__global__ __launch_bounds__(256) void k_prep(const float* __restrict__ W,
                                              unsigned short* __restrict__ Wbf) {
    int idx = (blockIdx.x * 256 + threadIdx.x) * 4;
    #pragma unroll
    for (int q = 0; q < 4; ++q) {
        int i = idx + q;            // i = k*128 + c
        int k = i >> 7, c = i & 127;
        Wbf[c * 128 + k] = (unsigned short)f2bf(W[i]);
    }
}

// ---------------------------------------------------------------------------
// Kernel A: h(bf16) = bf16(feats) @ W  via mfma_f32_16x16x32_bf16.
// B-fragments read straight from Wbf (32 KB, L1/L2-resident) — no LDS.
// el/er computed in the epilogue: tile ti == head ti (cols ti*16+m);
// butterfly-reduce acc*attn over the 16 m-lanes of each quad.
// ---------------------------------------------------------------------------
__global__ __launch_bounds__(256) void k_gemm(const float* __restrict__ feats,
                                              const unsigned short* __restrict__ Wbf,
                                              const float* __restrict__ attn_l,
                                              const float* __restrict__ attn_r,
                                              unsigned short* __restrict__ h,
                                              float* __restrict__ el,
                                              float* __restrict__ er,
                                              int N) {
    const int t    = threadIdx.x;
    const int n0   = blockIdx.x * 64;
    const int w    = t >> 6;
    const int lane = t & 63;
    const int m    = lane & 15;
    const int quad = lane >> 4;
    const int kq   = quad * 8;

    const int row_a = n0 + w * 16 + m;
    const bool va = (row_a < N);

    f32x4 acc[8];
    #pragma unroll
    for (int ti = 0; ti < 8; ++ti) acc[ti] = (f32x4){0.f, 0.f, 0.f, 0.f};

    #pragma unroll
    for (int kc = 0; kc < 4; ++kc) {
        const float* ap = feats + (size_t)row_a * 128 + kc * 32 + kq;
        float4 a0 = va ? ((const float4*)ap)[0] : make_float4(0.f,0.f,0.f,0.f);
        float4 a1 = va ? ((const float4*)ap)[1] : make_float4(0.f,0.f,0.f,0.f);
        bf16x8 af;
        af[0] = f2bf(a0.x); af[1] = f2bf(a0.y); af[2] = f2bf(a0.z); af[3] = f2bf(a0.w);
        af[4] = f2bf(a1.x); af[5] = f2bf(a1.y); af[6] = f2bf(a1.z); af[7] = f2bf(a1.w);
        #pragma unroll
        for (int ti = 0; ti < 8; ++ti) {
            bf16x8 bf = *(const bf16x8*)&Wbf[(size_t)(ti * 16 + m) * 128 + kc * 32 + kq];
            acc[ti] = __builtin_amdgcn_mfma_f32_16x16x32_bf16(af, bf, acc[ti], 0, 0, 0);
        }
    }

    // C layout: col = ti*16 + m, row = row_d + r  (r = reg idx)
    const int row_d = n0 + w * 16 + quad * 4;

    // h store
    #pragma unroll
    for (int ti = 0; ti < 8; ++ti) {
        int col = ti * 16 + m;
        #pragma unroll
        for (int r = 0; r < 4; ++r) {
            int row = row_d + r;
            if (row < N) h[(size_t)row * 128 + col] = (unsigned short)f2bf(acc[ti][r]);
        }
    }

    // fused el/er: el[row, ti] = sum_m acc[ti][r]*attn_l[ti*16+m]
    #pragma unroll
    for (int ti = 0; ti < 8; ++ti) {
        float al = attn_l[ti * 16 + m];
        float ar = attn_r[ti * 16 + m];
        #pragma unroll
        for (int r = 0; r < 4; ++r) {
            float vl = acc[ti][r] * al;
            float vr = acc[ti][r] * ar;
            vl += __shfl_xor(vl, 1); vr += __shfl_xor(vr, 1);
            vl += __shfl_xor(vl, 2); vr += __shfl_xor(vr, 2);
            vl += __shfl_xor(vl, 4); vr += __shfl_xor(vr, 4);
            vl += __shfl_xor(vl, 8); vr += __shfl_xor(vr, 8);
            int row = row_d + r;
            if (m == 0 && row < N) {
                el[row * 8 + ti] = vl;
                er[row * 8 + ti] = vr;
            }
        }
    }
}

// ---------------------------------------------------------------------------
// CSR build, dst-range partitioned (8 ranges ~ XCDs): block (chunk, range)
// keeps atomic lines and csr_src writebacks XCD-local / line-dense.
// ---------------------------------------------------------------------------
#define CHUNK 2048   // edges per block (256 thr x 8)

__global__ __launch_bounds__(256) void k_deg(const int* __restrict__ dst,
                                             int* __restrict__ deg,
                                             int E, int N8) {
    int r = blockIdx.x & 7;
    int c = blockIdx.x >> 3;
    int lo = r * N8, hi = lo + N8;
    int base = c * CHUNK + threadIdx.x;
    #pragma unroll
    for (int q = 0; q < 8; ++q) {
        int e = base + q * 256;
        if (e < E) {
            int d = dst[e];
            if (d >= lo && d < hi) atomicAdd(&deg[d], 1);
        }
    }
}

__global__ __launch_bounds__(256) void k_scan1(const int* __restrict__ deg,
                                               int* __restrict__ rowptr,
                                               int* __restrict__ partial, int N) {
    __shared__ int sd[256];
    int b = blockIdx.x, t = threadIdx.x;
    int base = b * 1024 + t * 4;
    int v0 = 0, v1 = 0, v2 = 0, v3 = 0;
    if (base + 3 < N) {
        int4 d4 = *(const int4*)(deg + base);
        v0 = d4.x; v1 = d4.y; v2 = d4.z; v3 = d4.w;
    } else {
        if (base + 0 < N) v0 = deg[base];
        if (base + 1 < N) v1 = deg[base + 1];
        if (base + 2 < N) v2 = deg[base + 2];
    }
    int tsum = v0 + v1 + v2 + v3;
    sd[t] = tsum;
    __syncthreads();
    for (int off = 1; off < 256; off <<= 1) {
        int x = (t >= off) ? sd[t - off] : 0;
        __syncthreads();
        sd[t] += x;
        __syncthreads();
    }
    int ex = sd[t] - tsum;
    if (base     < N) rowptr[base]     = ex;
    if (base + 1 < N) rowptr[base + 1] = ex + v0;
    if (base + 2 < N) rowptr[base + 2] = ex + v0 + v1;
    if (base + 3 < N) rowptr[base + 3] = ex + v0 + v1 + v2;
    if (t == 255) partial[b] = sd[255];
}

// parallel scan of up to 256 block partials (was a serial 1-thread loop)
__global__ __launch_bounds__(256) void k_scan2(const int* __restrict__ partial,
                                               int* __restrict__ partial_ex, int B) {
    __shared__ int sd[256];
    int t = threadIdx.x;
    int v = (t < B) ? partial[t] : 0;
    sd[t] = v;
    __syncthreads();
    for (int off = 1; off < 256; off <<= 1) {
        int x = (t >= off) ? sd[t - off] : 0;
        __syncthreads();
        sd[t] += x;
        __syncthreads();
    }
    if (t < B) partial_ex[t] = sd[t] - v;
}

__global__ __launch_bounds__(256) void k_scan3(int* __restrict__ rowptr,
                                               int* __restrict__ cursor,
                                               const int* __restrict__ partial_ex,
                                               int N, int E) {
    int b = blockIdx.x, t = threadIdx.x;
    int add = partial_ex[b];
    int base = b * 1024 + t * 4;
    #pragma unroll
    for (int q = 0; q < 4; ++q) {
        int i = base + q;
        if (i < N) { int v = rowptr[i] + add; rowptr[i] = v; cursor[i] = v; }
    }
    if (b == 0 && t == 0) rowptr[N] = E;
}

__global__ __launch_bounds__(256) void k_fill(const int* __restrict__ src,
                                              const int* __restrict__ dst,
                                              int* __restrict__ cursor,
                                              int* __restrict__ csr_src,
                                              int E, int N8) {
    int r = blockIdx.x & 7;
    int c = blockIdx.x >> 3;
    int lo = r * N8, hi = lo + N8;
    int base = c * CHUNK + threadIdx.x;
    #pragma unroll
    for (int q = 0; q < 8; ++q) {
        int e = base + q * 256;
        if (e < E) {
            int d = dst[e];
            if (d >= lo && d < hi) {
                int p = atomicAdd(&cursor[d], 1);
                csr_src[p] = src[e];
            }
        }
    }
}

// ---------------------------------------------------------------------------
// Kernel D: gather aggregation, one wave per node; quarter q handles edges
// begin+q, +4, ... with 2-edge unroll (8 edges in flight per wave).
// ---------------------------------------------------------------------------
__global__ __launch_bounds__(256) void k_agg(const int* __restrict__ rowptr,
                                             const int* __restrict__ csr_src,
                                             const float* __restrict__ el,
                                             const float* __restrict__ er,
                                             const unsigned short* __restrict__ h,
                                             const float* __restrict__ bias,
                                             float* __restrict__ out, int N) {
    int t = threadIdx.x;
    int n = blockIdx.x * 4 + (t >> 6);
    if (n >= N) return;
    int lane = t & 63;
    int q    = lane >> 4;      // edge slot 0..3
    int c16  = lane & 15;      // col group: cols 8*c16..8*c16+7
    int hd   = c16 >> 1;
    int begin = rowptr[n], end = rowptr[n + 1];
    float erv = er[n * 8 + hd];

    float acc[8] = {0.f,0.f,0.f,0.f,0.f,0.f,0.f,0.f};
    float expsum = 0.f;

    auto edge = [&](int p) {
        int s = csr_src[p];
        float x = el[s * 8 + hd] + erv;
        x = x > 0.f ? x : NEG * x;
        float w = __expf(x);
        expsum += w;
        uint4 hv = *(const uint4*)(h + (size_t)s * 128 + c16 * 8);
        acc[0] += w * bflo(hv.x); acc[1] += w * bfhi(hv.x);
        acc[2] += w * bflo(hv.y); acc[3] += w * bfhi(hv.y);
        acc[4] += w * bflo(hv.z); acc[5] += w * bfhi(hv.z);
        acc[6] += w * bflo(hv.w); acc[7] += w * bfhi(hv.w);
    };

    int p = begin + q;
    for (; p + 4 < end; p += 8) { edge(p); edge(p + 4); }
    if (p < end) edge(p);

    #pragma unroll
    for (int k = 0; k < 8; ++k) {
        acc[k] += __shfl_xor(acc[k], 32);
        acc[k] += __shfl_xor(acc[k], 16);
    }
    expsum += __shfl_xor(expsum, 32);
    expsum += __shfl_xor(expsum, 16);

    if (q == 0) {
        float inv = expsum > 0.f ? 1.f / expsum : 0.f;
        uint4 hn = *(const uint4*)(h + (size_t)n * 128 + c16 * 8);
        const float4* bp = (const float4*)(bias + c16 * 8);
        float4 b0 = bp[0], b1 = bp[1];
        float4 o0, o1;
        o0.x = acc[0]*inv + bflo(hn.x) + b0.x;
        o0.y = acc[1]*inv + bfhi(hn.x) + b0.y;
        o0.z = acc[2]*inv + bflo(hn.y) + b0.z;
        o0.w = acc[3]*inv + bfhi(hn.y) + b0.w;
        o1.x = acc[4]*inv + bflo(hn.z) + b1.x;
        o1.y = acc[5]*inv + bfhi(hn.z) + b1.y;
        o1.z = acc[6]*inv + bflo(hn.w) + b1.z;
        o1.w = acc[7]*inv + bfhi(hn.w) + b1.w;
        float4* op = (float4*)(out + (size_t)n * 128 + c16 * 8);
        op[0] = o0; op[1] = o1;
    }
}

extern "C" void kernel_launch(void* const* d_in, const int* in_sizes, int n_in,
                              void* d_out, int out_size, void* d_ws, size_t ws_size,
                              hipStream_t stream) {
    const float* feats  = (const float*)d_in[0];
    const float* W      = (const float*)d_in[1];
    const float* attn_l = (const float*)d_in[2];
    const float* attn_r = (const float*)d_in[3];
    const float* bias   = (const float*)d_in[4];
    const int*   src    = (const int*)d_in[5];
    const int*   dst    = (const int*)d_in[6];

    const int N = in_sizes[0] / 128;
    const int E = in_sizes[5];
    const int B1 = (N + 1023) / 1024;
    const int N8 = (N + 7) / 8;
    const int CH = (E + CHUNK - 1) / CHUNK;

    float* out = (float*)d_out;
    char*  ws  = (char*)d_ws;
    unsigned short* Wbf = (unsigned short*)ws;         ws += 128 * 128 * 2;
    unsigned short* h = (unsigned short*)ws;           ws += (size_t)N * 128 * 2;
    float* el      = (float*)ws;                       ws += (size_t)N * 8 * 4;
    float* er      = (float*)ws;                       ws += (size_t)N * 8 * 4;
    int*   deg     = (int*)ws;                         ws += (size_t)N * 4;
    int*   rowptr  = (int*)ws;                         ws += (size_t)(N + 1) * 4;
    int*   cursor  = (int*)ws;                         ws += (size_t)N * 4;
    int*   partial = (int*)ws;                         ws += 256 * 4;
    int*   partial_ex = (int*)ws;                      ws += 256 * 4;
    int*   csr_src = (int*)ws;                         ws += (size_t)E * 4;

    hipMemsetAsync(deg, 0, (size_t)N * sizeof(int), stream);

    k_prep <<<16,                    256, 0, stream>>>(W, Wbf);
    k_gemm <<<(N + 63) / 64,         256, 0, stream>>>(feats, Wbf, attn_l, attn_r, h, el, er, N);
    k_deg  <<<CH * 8,                256, 0, stream>>>(dst, deg, E, N8);
    k_scan1<<<B1,                    256, 0, stream>>>(deg, rowptr, partial, N);
    k_scan2<<<1,                     256, 0, stream>>>(partial, partial_ex, B1);
    k_scan3<<<B1,                    256, 0, stream>>>(rowptr, cursor, partial_ex, N, E);
    k_fill <<<CH * 8,                256, 0, stream>>>(src, dst, cursor, csr_src, E, N8);
    k_agg  <<<(N + 3) / 4,           256, 0, stream>>>(rowptr, csr_src, el, er, h, bias, out, N);
}